// Round 1
// baseline (963.078 us; speedup 1.0000x reference)
//
#include <hip/hip_runtime.h>
#include <math.h>

// SoftGate: gate-MLP (split-bf16 MFMA, pipelined) -> threshold -> compaction.
#define NB 8
#define NS 4096
#define ND 1024      // K (feature dim)
#define NDH 512      // N (hidden dim)
#define NTOK (NB*NS) // M = 32768
#define THRESH 0.1f
#define EPSV 1e-5f

using short8   = __attribute__((ext_vector_type(8)))  short;
using floatx16 = __attribute__((ext_vector_type(16))) float;
using floatv4  = __attribute__((ext_vector_type(4)))  float;  // native vec for nontemporal

__device__ __forceinline__ unsigned short f32_to_bf16_rne(float f) {
  union { float f; unsigned u; } v; v.f = f;
  unsigned r = v.u + 0x7fffu + ((v.u >> 16) & 1u);
  return (unsigned short)(r >> 16);
}
__device__ __forceinline__ float bf16_to_f32(unsigned short h) {
  union { unsigned u; float f; } v; v.u = ((unsigned)h) << 16;
  return v.f;
}

// ---------------------------------------------------------------------------
// K0: repack W1 into MFMA-B-fragment order, bf16 hi/lo by 1 KB chunk:
//   chunk(n32,k16): lane l holds n=n32*32+(l&31), k=k16*16+(l>>5)*8+j.
// Also zero-inits rowmax for k1's fused atomicMax.
// ---------------------------------------------------------------------------
__global__ __launch_bounds__(256)
void k0_prep(const float* __restrict__ W1, unsigned short* __restrict__ Wf,
             unsigned int* __restrict__ rowmax) {
  __shared__ float sw[16][513];
  const int t = threadIdx.x;
  const int k16 = blockIdx.x;                // 0..63
  if (k16 == 0 && t < NB) rowmax[t] = 0u;
#pragma unroll
  for (int i = 0; i < 8; ++i) {
    int flat = i * 256 + t;
    int r = flat >> 7, c4 = (flat & 127) << 2;
    *(float4*)&sw[r][c4] = *(const float4*)(W1 + (size_t)(k16 * 16 + r) * NDH + c4);
  }
  __syncthreads();
#pragma unroll
  for (int q = 0; q < 4; ++q) {
    int ss = q * 256 + t;
    int n32 = ss >> 6, lane = ss & 63;
    int n = n32 * 32 + (lane & 31);
    int kb = (lane >> 5) * 8;
    unsigned hi2[4], lo2[4];
#pragma unroll
    for (int j = 0; j < 4; ++j) {
      float w0 = sw[kb + 2 * j][n], w1 = sw[kb + 2 * j + 1][n];
      unsigned short h0 = f32_to_bf16_rne(w0), h1 = f32_to_bf16_rne(w1);
      unsigned short l0 = f32_to_bf16_rne(w0 - bf16_to_f32(h0));
      unsigned short l1 = f32_to_bf16_rne(w1 - bf16_to_f32(h1));
      hi2[j] = (unsigned)h0 | ((unsigned)h1 << 16);
      lo2[j] = (unsigned)l0 | ((unsigned)l1 << 16);
    }
    size_t cb = ((size_t)(n32 * 64 + k16) * 2) * 512 + (size_t)lane * 8;
    *(uint4*)(Wf + cb)       = make_uint4(hi2[0], hi2[1], hi2[2], hi2[3]);
    *(uint4*)(Wf + cb + 512) = make_uint4(lo2[0], lo2[1], lo2[2], lo2[3]);
  }
}

// ---------------------------------------------------------------------------
// K1: fused gate MLP. 3-term split-bf16 MFMA (hi·hi + lo·hi + hi·lo), fp32 acc.
// 8-wave blocks on the same 64x512 tile: wave w owns cols [64w,64w+64).
// Rationale (R6): the 256-thread version was grid-capped at 2 waves/SIMD
// (Occupancy ~20%) -- matrix pipe idled through B-load L2 latency + convert
// tail + barrier skew (MfmaUtil 37% = m97 plateau). 8-wave blocks give
// 4 waves/SIMD from 2 phase-independent blocks/CU, halve per-wave B loads
// (8 vs 16) and halve acc regs (64 vs 128). Per-acc MFMA order unchanged
// (kh0: hh,lh,hl; kh1: hh,lh,hl) -> same accumulation as R5.
// setprio(1) around the MFMA cluster (T5): pays only with phase diversity,
// which the 2 independent blocks now provide.
// Tail fuses squash(tanh)+pad-zero+ysq store+atomicMax rowmax (exact max ->
// deterministic). BM=64 x N=512, BK=32.
// ---------------------------------------------------------------------------
__global__ __launch_bounds__(512, 4)
void k1_gemm(const float* __restrict__ x, const unsigned short* __restrict__ Wf,
             const float* __restrict__ b1, const float* __restrict__ W2,
             const int* __restrict__ pad, const float* __restrict__ b2,
             float* __restrict__ ysq, unsigned int* __restrict__ rowmax) {
  __shared__ __align__(16) unsigned short sx[2][2][64 * 40];  // [buf][hi/lo][m*40+k]
  __shared__ float red[8][64];

  const int tid = threadIdx.x;
  const int wave = tid >> 6, lane = tid & 63;
  const int l31 = lane & 31, h5 = lane >> 5;
  const int tok0 = blockIdx.x * 64;

  floatx16 acc[2][2];
#pragma unroll
  for (int mt = 0; mt < 2; ++mt)
#pragma unroll
    for (int nt = 0; nt < 2; ++nt)
#pragma unroll
      for (int r = 0; r < 16; ++r) acc[mt][nt][r] = 0.f;

  const int sm = tid >> 3;            // staging row 0..63 (8 threads/row)
  const int sk = (tid & 7) * 4;       // staging k-offset {0,4,...,28}
  const float* xrow = x + (size_t)(tok0 + sm) * ND + sk;

  const unsigned short* wb[2];
#pragma unroll
  for (int nt = 0; nt < 2; ++nt)
    wb[nt] = Wf + (((size_t)(wave * 2 + nt) * 64) * 2) * 512 + (size_t)lane * 8;

  // prologue: stage x for it=0 into LDS buf 0 (4 floats/thread)
  {
    float4 xa = *(const float4*)xrow;
    float v4[4] = {xa.x, xa.y, xa.z, xa.w};
    unsigned hp[2], lp[2];
#pragma unroll
    for (int j = 0; j < 2; ++j) {
      unsigned short h0 = f32_to_bf16_rne(v4[2 * j]);
      unsigned short h1 = f32_to_bf16_rne(v4[2 * j + 1]);
      unsigned short l0 = f32_to_bf16_rne(v4[2 * j] - bf16_to_f32(h0));
      unsigned short l1 = f32_to_bf16_rne(v4[2 * j + 1] - bf16_to_f32(h1));
      hp[j] = (unsigned)h0 | ((unsigned)h1 << 16);
      lp[j] = (unsigned)l0 | ((unsigned)l1 << 16);
    }
    *(uint2*)&sx[0][0][sm * 40 + sk] = make_uint2(hp[0], hp[1]);
    *(uint2*)&sx[0][1][sm * 40 + sk] = make_uint2(lp[0], lp[1]);
  }

  for (int it = 0; it < 32; ++it) {
    const int p = it & 1;
    __syncthreads();                  // LDS[p] ready; prev-iter prefetch drained
    // B fragments for THIS iter: issued now, consumed below in load order ->
    // compiler emits progressive vmcnt waits, first MFMA covers ~L2 latency.
    short8 bh[2][2], bl[2][2];
#pragma unroll
    for (int nt = 0; nt < 2; ++nt)
#pragma unroll
      for (int kh = 0; kh < 2; ++kh) {
        const unsigned short* q = wb[nt] + ((size_t)(2 * it + kh) * 2) * 512;
        bh[nt][kh] = *(const short8*)(q);
        bl[nt][kh] = *(const short8*)(q + 512);
      }
    // x prefetch for NEXT iter: ~900-cyc HBM latency hides behind MFMA phase
    float4 pxa;
    if (it < 31) {
      const float* xp = xrow + (it + 1) * 32;
      pxa = *(const float4*)xp;
    }
    // A fragments: lane holds x[tok=mt*32+l31][k = kh*16 + h5*8 + j]
    short8 ah[2][2], al[2][2];
#pragma unroll
    for (int mt = 0; mt < 2; ++mt)
#pragma unroll
      for (int kh = 0; kh < 2; ++kh) {
        ah[mt][kh] = *(const short8*)&sx[p][0][(mt * 32 + l31) * 40 + kh * 16 + h5 * 8];
        al[mt][kh] = *(const short8*)&sx[p][1][(mt * 32 + l31) * 40 + kh * 16 + h5 * 8];
      }
    // term-outer MFMA issue: 4 independent accs between same-acc reuse
    __builtin_amdgcn_s_setprio(1);
#pragma unroll
    for (int kh = 0; kh < 2; ++kh) {
#pragma unroll
      for (int nt = 0; nt < 2; ++nt)
#pragma unroll
        for (int mt = 0; mt < 2; ++mt)
          acc[mt][nt] = __builtin_amdgcn_mfma_f32_32x32x16_bf16(ah[mt][kh], bh[nt][kh], acc[mt][nt], 0, 0, 0);
#pragma unroll
      for (int nt = 0; nt < 2; ++nt)
#pragma unroll
        for (int mt = 0; mt < 2; ++mt)
          acc[mt][nt] = __builtin_amdgcn_mfma_f32_32x32x16_bf16(al[mt][kh], bh[nt][kh], acc[mt][nt], 0, 0, 0);
#pragma unroll
      for (int nt = 0; nt < 2; ++nt)
#pragma unroll
        for (int mt = 0; mt < 2; ++mt)
          acc[mt][nt] = __builtin_amdgcn_mfma_f32_32x32x16_bf16(ah[mt][kh], bl[nt][kh], acc[mt][nt], 0, 0, 0);
    }
    __builtin_amdgcn_s_setprio(0);
    // convert prefetched x -> other LDS buffer (ready for next barrier)
    if (it < 31) {
      float v4[4] = {pxa.x, pxa.y, pxa.z, pxa.w};
      unsigned hp[2], lp[2];
#pragma unroll
      for (int j = 0; j < 2; ++j) {
        unsigned short h0 = f32_to_bf16_rne(v4[2 * j]);
        unsigned short h1 = f32_to_bf16_rne(v4[2 * j + 1]);
        unsigned short l0 = f32_to_bf16_rne(v4[2 * j] - bf16_to_f32(h0));
        unsigned short l1 = f32_to_bf16_rne(v4[2 * j + 1] - bf16_to_f32(h1));
        hp[j] = (unsigned)h0 | ((unsigned)h1 << 16);
        lp[j] = (unsigned)l0 | ((unsigned)l1 << 16);
      }
      *(uint2*)&sx[p ^ 1][0][sm * 40 + sk] = make_uint2(hp[0], hp[1]);
      *(uint2*)&sx[p ^ 1][1][sm * 40 + sk] = make_uint2(lp[0], lp[1]);
    }
  }

  // epilogue: relu(h+b1)*W2, shfl-reduce 32 col-lanes, LDS combine over 8 waves.
  // C/D layout (m74/m101): col=lane&31, row=(r&3)+8*(r>>2)+4*(lane>>5)
  float b1v[2], w2v[2];
#pragma unroll
  for (int nt = 0; nt < 2; ++nt) {
    const int n = wave * 64 + nt * 32 + l31;
    b1v[nt] = b1[n];
    w2v[nt] = W2[n];
  }
#pragma unroll
  for (int mt = 0; mt < 2; ++mt) {
    float pr[16];
#pragma unroll
    for (int r = 0; r < 16; ++r) pr[r] = 0.f;
#pragma unroll
    for (int nt = 0; nt < 2; ++nt)
#pragma unroll
      for (int r = 0; r < 16; ++r)
        pr[r] += fmaxf(acc[mt][nt][r] + b1v[nt], 0.f) * w2v[nt];
#pragma unroll
    for (int m = 1; m <= 16; m <<= 1)
#pragma unroll
      for (int r = 0; r < 16; ++r) pr[r] += __shfl_xor(pr[r], m, 64);
    if (l31 == 0) {
#pragma unroll
      for (int r = 0; r < 16; ++r) {
        int row = (r & 3) + 8 * (r >> 2) + 4 * h5;
        red[wave][mt * 32 + row] = pr[r];
      }
    }
  }
  __syncthreads();
  // fused k2a: squash, pad-zero, store ysq, exact row max via atomicMax
  if (tid < 64) {
    float s = red[0][tid] + red[1][tid] + red[2][tid] + red[3][tid]
            + red[4][tid] + red[5][tid] + red[6][tid] + red[7][tid];
    const int t = tok0 + tid;
    float yl = s + b2[0];
    float y = (1.f + tanhf(10.f * yl)) * 0.5f;
    if (pad[t]) y = 0.f;
    ysq[t] = y;
    float m = y;
#pragma unroll
    for (int o = 32; o >= 1; o >>= 1) m = fmaxf(m, __shfl_xor(m, o, 64));
    if (tid == 0) atomicMax(rowmax + (t >> 12), __float_as_uint(m));
  }
}

// ---------------------------------------------------------------------------
// K2b: per row -- adjust, threshold, stable shfl-scan compaction map, new_len,
// v_pad, and gate value packed by DEST index (gval) so k3 reads it directly.
// ---------------------------------------------------------------------------
__global__ __launch_bounds__(256)
void k2b(const float* __restrict__ ysq, const int* __restrict__ pad,
         const unsigned int* __restrict__ rowmax, float* __restrict__ gval,
         int* __restrict__ src_of_dest, int* __restrict__ new_len,
         float* __restrict__ vpad_out) {
  __shared__ int ssum[4];
  const int b = blockIdx.x, tid = threadIdx.x;
  const int lane = tid & 63, wv = tid >> 6;
  const int base = b * NS, s0 = tid * 16;
  const float adj = fmaxf(EPSV + THRESH - __uint_as_float(rowmax[b]), 0.f);

  float yv[16];
  unsigned km = 0;
  int cnt = 0;
#pragma unroll
  for (int i = 0; i < 16; ++i) {
    int s = s0 + i;
    float yf = ysq[base + s] + adj;
    yv[i] = yf;
    bool keep = (yf > THRESH) && !pad[base + s];
    if (keep) { km |= (1u << i); ++cnt; }
  }
  // wave inclusive scan of per-thread counts
  int inc = cnt;
#pragma unroll
  for (int o = 1; o < 64; o <<= 1) {
    int tmp = __shfl_up(inc, o, 64);
    if (lane >= o) inc += tmp;
  }
  if (lane == 63) ssum[wv] = inc;
  __syncthreads();
  int wpre = 0;
  for (int w = 0; w < wv; ++w) wpre += ssum[w];
  const int total = ssum[0] + ssum[1] + ssum[2] + ssum[3];
  int off = wpre + inc - cnt;   // exclusive offset, stable order
#pragma unroll
  for (int i = 0; i < 16; ++i) {
    int s = s0 + i;
    if ((km >> i) & 1u) {
      src_of_dest[base + off] = s;
      gval[base + off] = yv[i];
      ++off;
    }
    vpad_out[base + s] = (s >= total) ? 1.f : 0.f;
  }
  if (tid == 0) new_len[b] = total;
}

// ---------------------------------------------------------------------------
// K3: 16 output slots per block (2048 blocks): v = x[src]*gval or zeros.
// Nontemporal stores (native ext_vector float4) -- v is written once.
// ---------------------------------------------------------------------------
__global__ __launch_bounds__(256)
void k3_gather(const float* __restrict__ x, const float* __restrict__ gval,
               const int* __restrict__ src_of_dest, const int* __restrict__ new_len,
               float* __restrict__ v) {
  const int slot0 = blockIdx.x * 16;
  const int b = slot0 >> 12;            // 16 | 4096 -> same row for all 16
  const int nl = new_len[b];
  const int tid = threadIdx.x;
#pragma unroll
  for (int i = 0; i < 16; ++i) {
    const int slot = slot0 + i;
    const int dest = slot & (NS - 1);
    floatv4* vo = (floatv4*)(v + (size_t)slot * ND);
    floatv4 r;
    if (dest < nl) {
      const int src = src_of_dest[slot];
      const float g = gval[slot];
      floatv4 xv = ((const floatv4*)(x + ((size_t)b * NS + src) * ND))[tid];
      r = xv * g;
    } else {
      r = (floatv4)(0.f);
    }
    __builtin_nontemporal_store(r, vo + tid);
  }
}

extern "C" void kernel_launch(void* const* d_in, const int* in_sizes, int n_in,
                              void* d_out, int out_size, void* d_ws, size_t ws_size,
                              hipStream_t stream) {
  const float* x   = (const float*)d_in[0];
  const int*   pad = (const int*)d_in[1];
  const float* W1  = (const float*)d_in[2];
  const float* b1  = (const float*)d_in[3];
  const float* W2  = (const float*)d_in[4];
  const float* b2  = (const float*)d_in[5];

  float* v    = (float*)d_out;                 // [8,4096,1024]
  float* vpad = v + (size_t)NTOK * ND;         // [8,4096]

  // Wf scratch inside d_out's v region: k1 reads it, k3 later overwrites all
  // of v (same-stream ordering makes this safe, incl. rocprof replay).
  unsigned short* Wf = (unsigned short*)(v + 24000000);  // 2 MB packed W

  // d_ws (~384 KB): ysq, gval, src map, new_len, rowmax
  float* ysq  = (float*)d_ws;                  // NTOK
  float* gval = ysq + NTOK;                    // NTOK
  int* src    = (int*)(gval + NTOK);           // NTOK
  int* nlen   = src + NTOK;                    // NB
  unsigned int* rowmax = (unsigned int*)(nlen + NB);  // NB

  k0_prep<<<64, 256, 0, stream>>>(W1, Wf, rowmax);
  k1_gemm<<<NTOK / 64, 512, 0, stream>>>(x, Wf, b1, W2, pad, b2, ysq, rowmax);
  k2b<<<NB, 256, 0, stream>>>(ysq, pad, rowmax, gval, src, nlen, vpad);
  k3_gather<<<NTOK / 16, 256, 0, stream>>>(x, gval, src, nlen, v);
}

// Round 2
// 357.192 us; speedup vs baseline: 2.6962x; 2.6962x over previous
//
#include <hip/hip_runtime.h>
#include <math.h>

// SoftGate: gate-MLP (split-bf16 MFMA, pipelined) -> threshold -> compaction.
#define NB 8
#define NS 4096
#define ND 1024      // K (feature dim)
#define NDH 512      // N (hidden dim)
#define NTOK (NB*NS) // M = 32768
#define THRESH 0.1f
#define EPSV 1e-5f

using short8   = __attribute__((ext_vector_type(8)))  short;
using floatx16 = __attribute__((ext_vector_type(16))) float;
using floatv4  = __attribute__((ext_vector_type(4)))  float;  // native vec for nontemporal

__device__ __forceinline__ unsigned short f32_to_bf16_rne(float f) {
  union { float f; unsigned u; } v; v.f = f;
  unsigned r = v.u + 0x7fffu + ((v.u >> 16) & 1u);
  return (unsigned short)(r >> 16);
}
__device__ __forceinline__ float bf16_to_f32(unsigned short h) {
  union { unsigned u; float f; } v; v.u = ((unsigned)h) << 16;
  return v.f;
}

// ---------------------------------------------------------------------------
// K0: repack W1 into MFMA-B-fragment order, bf16 hi/lo by 1 KB chunk:
//   chunk(n32,k16): lane l holds n=n32*32+(l&31), k=k16*16+(l>>5)*8+j.
// Also zero-inits rowmax for k1's fused atomicMax.  (identical to R5)
// ---------------------------------------------------------------------------
__global__ __launch_bounds__(256)
void k0_prep(const float* __restrict__ W1, unsigned short* __restrict__ Wf,
             unsigned int* __restrict__ rowmax) {
  __shared__ float sw[16][513];
  const int t = threadIdx.x;
  const int k16 = blockIdx.x;                // 0..63
  if (k16 == 0 && t < NB) rowmax[t] = 0u;
#pragma unroll
  for (int i = 0; i < 8; ++i) {
    int flat = i * 256 + t;
    int r = flat >> 7, c4 = (flat & 127) << 2;
    *(float4*)&sw[r][c4] = *(const float4*)(W1 + (size_t)(k16 * 16 + r) * NDH + c4);
  }
  __syncthreads();
#pragma unroll
  for (int q = 0; q < 4; ++q) {
    int ss = q * 256 + t;
    int n32 = ss >> 6, lane = ss & 63;
    int n = n32 * 32 + (lane & 31);
    int kb = (lane >> 5) * 8;
    unsigned hi2[4], lo2[4];
#pragma unroll
    for (int j = 0; j < 4; ++j) {
      float w0 = sw[kb + 2 * j][n], w1 = sw[kb + 2 * j + 1][n];
      unsigned short h0 = f32_to_bf16_rne(w0), h1 = f32_to_bf16_rne(w1);
      unsigned short l0 = f32_to_bf16_rne(w0 - bf16_to_f32(h0));
      unsigned short l1 = f32_to_bf16_rne(w1 - bf16_to_f32(h1));
      hi2[j] = (unsigned)h0 | ((unsigned)h1 << 16);
      lo2[j] = (unsigned)l0 | ((unsigned)l1 << 16);
    }
    size_t cb = ((size_t)(n32 * 64 + k16) * 2) * 512 + (size_t)lane * 8;
    *(uint4*)(Wf + cb)       = make_uint4(hi2[0], hi2[1], hi2[2], hi2[3]);
    *(uint4*)(Wf + cb + 512) = make_uint4(lo2[0], lo2[1], lo2[2], lo2[3]);
  }
}

// ---------------------------------------------------------------------------
// K1: fused gate MLP. 3-term split-bf16 MFMA (hi·hi + lo·hi + hi·lo), fp32 acc.
// R7: R5 structure with BM 64->32. Rationale: R5 was grid-capped at 2 blocks/CU
// = 2 waves/SIMD (Occupancy 20%, MfmaUtil 37% latency plateau). BM=32 halves
// acc (128->64 AGPR) and A-frags -> unified regs ~167 <= 170, so THREE
// 256-thread blocks co-reside per CU (3 waves/SIMD, each from an independent
// block -> cross-block phase diversity hides B-L2 latency + convert tail).
// launch_bounds(256,3) caps at 170 (needed shave ~0-5 regs; R6's disaster was
// a forced -22 acc spill -- tripwire: WRITE_SIZE must stay ~KB).
// Per-acc MFMA accumulation order unchanged (kh0: hh,lh,hl; kh1: hh,lh,hl).
// Tail fuses squash(tanh)+pad-zero+ysq store+atomicMax rowmax (exact max).
// BM=32 x N=512, BK=32; wave w owns cols [128w,128w+128).
// ---------------------------------------------------------------------------
__global__ __launch_bounds__(256, 3)
void k1_gemm(const float* __restrict__ x, const unsigned short* __restrict__ Wf,
             const float* __restrict__ b1, const float* __restrict__ W2,
             const int* __restrict__ pad, const float* __restrict__ b2,
             float* __restrict__ ysq, unsigned int* __restrict__ rowmax) {
  __shared__ __align__(16) unsigned short sx[2][2][32 * 40];  // [buf][hi/lo][m*40+k]
  __shared__ float red[4][32];

  const int tid = threadIdx.x;
  const int wave = tid >> 6, lane = tid & 63;
  const int l31 = lane & 31, h5 = lane >> 5;
  const int tok0 = blockIdx.x * 32;

  floatx16 acc[4];
#pragma unroll
  for (int nt = 0; nt < 4; ++nt)
#pragma unroll
    for (int r = 0; r < 16; ++r) acc[nt][r] = 0.f;

  const int sm = tid >> 3;            // staging row 0..31 (8 threads/row)
  const int sk = (tid & 7) * 4;       // staging k-offset {0,4,...,28}
  const float* xrow = x + (size_t)(tok0 + sm) * ND + sk;

  const unsigned short* wb[4];
#pragma unroll
  for (int nt = 0; nt < 4; ++nt)
    wb[nt] = Wf + (((size_t)(wave * 4 + nt) * 64) * 2) * 512 + (size_t)lane * 8;

  // prologue: stage x for it=0 into LDS buf 0 (4 floats/thread)
  {
    float4 xa = *(const float4*)xrow;
    unsigned short h0 = f32_to_bf16_rne(xa.x);
    unsigned short h1 = f32_to_bf16_rne(xa.y);
    unsigned short h2 = f32_to_bf16_rne(xa.z);
    unsigned short h3 = f32_to_bf16_rne(xa.w);
    unsigned short l0 = f32_to_bf16_rne(xa.x - bf16_to_f32(h0));
    unsigned short l1 = f32_to_bf16_rne(xa.y - bf16_to_f32(h1));
    unsigned short l2 = f32_to_bf16_rne(xa.z - bf16_to_f32(h2));
    unsigned short l3 = f32_to_bf16_rne(xa.w - bf16_to_f32(h3));
    *(uint2*)&sx[0][0][sm * 40 + sk] =
        make_uint2((unsigned)h0 | ((unsigned)h1 << 16), (unsigned)h2 | ((unsigned)h3 << 16));
    *(uint2*)&sx[0][1][sm * 40 + sk] =
        make_uint2((unsigned)l0 | ((unsigned)l1 << 16), (unsigned)l2 | ((unsigned)l3 << 16));
  }

  for (int it = 0; it < 32; ++it) {
    const int p = it & 1;
    __syncthreads();                  // LDS[p] ready; prev-iter prefetch drained
    // B fragments for THIS iter: issued now, consumed below in load order ->
    // compiler emits progressive vmcnt waits, first MFMA covers ~L2 latency.
    short8 bh[4][2], bl[4][2];
#pragma unroll
    for (int nt = 0; nt < 4; ++nt)
#pragma unroll
      for (int kh = 0; kh < 2; ++kh) {
        const unsigned short* q = wb[nt] + ((size_t)(2 * it + kh) * 2) * 512;
        bh[nt][kh] = *(const short8*)(q);
        bl[nt][kh] = *(const short8*)(q + 512);
      }
    // x prefetch for NEXT iter: ~900-cyc HBM latency hides behind MFMA phase
    float4 pxa;
    if (it < 31) {
      const float* xp = xrow + (it + 1) * 32;
      pxa = *(const float4*)xp;
    }
    // A fragments: lane holds x[tok=l31][k = kh*16 + h5*8 + j]
    short8 ah[2], al[2];
#pragma unroll
    for (int kh = 0; kh < 2; ++kh) {
      ah[kh] = *(const short8*)&sx[p][0][l31 * 40 + kh * 16 + h5 * 8];
      al[kh] = *(const short8*)&sx[p][1][l31 * 40 + kh * 16 + h5 * 8];
    }
    // term-outer MFMA issue: 4 independent accs between same-acc reuse
#pragma unroll
    for (int kh = 0; kh < 2; ++kh) {
#pragma unroll
      for (int nt = 0; nt < 4; ++nt)
        acc[nt] = __builtin_amdgcn_mfma_f32_32x32x16_bf16(ah[kh], bh[nt][kh], acc[nt], 0, 0, 0);
#pragma unroll
      for (int nt = 0; nt < 4; ++nt)
        acc[nt] = __builtin_amdgcn_mfma_f32_32x32x16_bf16(al[kh], bh[nt][kh], acc[nt], 0, 0, 0);
#pragma unroll
      for (int nt = 0; nt < 4; ++nt)
        acc[nt] = __builtin_amdgcn_mfma_f32_32x32x16_bf16(ah[kh], bl[nt][kh], acc[nt], 0, 0, 0);
    }
    // convert prefetched x -> other LDS buffer (ready for next barrier)
    if (it < 31) {
      unsigned short h0 = f32_to_bf16_rne(pxa.x);
      unsigned short h1 = f32_to_bf16_rne(pxa.y);
      unsigned short h2 = f32_to_bf16_rne(pxa.z);
      unsigned short h3 = f32_to_bf16_rne(pxa.w);
      unsigned short l0 = f32_to_bf16_rne(pxa.x - bf16_to_f32(h0));
      unsigned short l1 = f32_to_bf16_rne(pxa.y - bf16_to_f32(h1));
      unsigned short l2 = f32_to_bf16_rne(pxa.z - bf16_to_f32(h2));
      unsigned short l3 = f32_to_bf16_rne(pxa.w - bf16_to_f32(h3));
      *(uint2*)&sx[p ^ 1][0][sm * 40 + sk] =
          make_uint2((unsigned)h0 | ((unsigned)h1 << 16), (unsigned)h2 | ((unsigned)h3 << 16));
      *(uint2*)&sx[p ^ 1][1][sm * 40 + sk] =
          make_uint2((unsigned)l0 | ((unsigned)l1 << 16), (unsigned)l2 | ((unsigned)l3 << 16));
    }
  }

  // epilogue: relu(h+b1)*W2, shfl-reduce 32 col-lanes, LDS combine.
  // C/D layout (m74/m101): col=lane&31, row=(r&3)+8*(r>>2)+4*(lane>>5)
  float b1v[4], w2v[4];
#pragma unroll
  for (int nt = 0; nt < 4; ++nt) {
    const int n = wave * 128 + nt * 32 + l31;
    b1v[nt] = b1[n];
    w2v[nt] = W2[n];
  }
  {
    float pr[16];
#pragma unroll
    for (int r = 0; r < 16; ++r) pr[r] = 0.f;
#pragma unroll
    for (int nt = 0; nt < 4; ++nt)
#pragma unroll
      for (int r = 0; r < 16; ++r)
        pr[r] += fmaxf(acc[nt][r] + b1v[nt], 0.f) * w2v[nt];
#pragma unroll
    for (int m = 1; m <= 16; m <<= 1)
#pragma unroll
      for (int r = 0; r < 16; ++r) pr[r] += __shfl_xor(pr[r], m, 64);
    if (l31 == 0) {
#pragma unroll
      for (int r = 0; r < 16; ++r) {
        int row = (r & 3) + 8 * (r >> 2) + 4 * h5;
        red[wave][row] = pr[r];
      }
    }
  }
  __syncthreads();
  // fused k2a: squash, pad-zero, store ysq, exact row max via atomicMax
  if (tid < 32) {
    float s = red[0][tid] + red[1][tid] + red[2][tid] + red[3][tid];
    const int t = tok0 + tid;
    float yl = s + b2[0];
    float y = (1.f + tanhf(10.f * yl)) * 0.5f;
    if (pad[t]) y = 0.f;
    ysq[t] = y;
    float m = y;
#pragma unroll
    for (int o = 16; o >= 1; o >>= 1) m = fmaxf(m, __shfl_xor(m, o, 64));
    if (tid == 0) atomicMax(rowmax + (t >> 12), __float_as_uint(m));
  }
}

// ---------------------------------------------------------------------------
// K2b: per row -- adjust, threshold, stable shfl-scan compaction map, new_len,
// v_pad, and gate value packed by DEST index (gval) so k3 reads it directly.
// (identical to R5)
// ---------------------------------------------------------------------------
__global__ __launch_bounds__(256)
void k2b(const float* __restrict__ ysq, const int* __restrict__ pad,
         const unsigned int* __restrict__ rowmax, float* __restrict__ gval,
         int* __restrict__ src_of_dest, int* __restrict__ new_len,
         float* __restrict__ vpad_out) {
  __shared__ int ssum[4];
  const int b = blockIdx.x, tid = threadIdx.x;
  const int lane = tid & 63, wv = tid >> 6;
  const int base = b * NS, s0 = tid * 16;
  const float adj = fmaxf(EPSV + THRESH - __uint_as_float(rowmax[b]), 0.f);

  float yv[16];
  unsigned km = 0;
  int cnt = 0;
#pragma unroll
  for (int i = 0; i < 16; ++i) {
    int s = s0 + i;
    float yf = ysq[base + s] + adj;
    yv[i] = yf;
    bool keep = (yf > THRESH) && !pad[base + s];
    if (keep) { km |= (1u << i); ++cnt; }
  }
  // wave inclusive scan of per-thread counts
  int inc = cnt;
#pragma unroll
  for (int o = 1; o < 64; o <<= 1) {
    int tmp = __shfl_up(inc, o, 64);
    if (lane >= o) inc += tmp;
  }
  if (lane == 63) ssum[wv] = inc;
  __syncthreads();
  int wpre = 0;
  for (int w = 0; w < wv; ++w) wpre += ssum[w];
  const int total = ssum[0] + ssum[1] + ssum[2] + ssum[3];
  int off = wpre + inc - cnt;   // exclusive offset, stable order
#pragma unroll
  for (int i = 0; i < 16; ++i) {
    int s = s0 + i;
    if ((km >> i) & 1u) {
      src_of_dest[base + off] = s;
      gval[base + off] = yv[i];
      ++off;
    }
    vpad_out[base + s] = (s >= total) ? 1.f : 0.f;
  }
  if (tid == 0) new_len[b] = total;
}

// ---------------------------------------------------------------------------
// K3: 16 output slots per block (2048 blocks): v = x[src]*gval or zeros.
// Nontemporal stores (native ext_vector float4) -- v is written once.
// (identical to R5)
// ---------------------------------------------------------------------------
__global__ __launch_bounds__(256)
void k3_gather(const float* __restrict__ x, const float* __restrict__ gval,
               const int* __restrict__ src_of_dest, const int* __restrict__ new_len,
               float* __restrict__ v) {
  const int slot0 = blockIdx.x * 16;
  const int b = slot0 >> 12;            // 16 | 4096 -> same row for all 16
  const int nl = new_len[b];
  const int tid = threadIdx.x;
#pragma unroll
  for (int i = 0; i < 16; ++i) {
    const int slot = slot0 + i;
    const int dest = slot & (NS - 1);
    floatv4* vo = (floatv4*)(v + (size_t)slot * ND);
    floatv4 r;
    if (dest < nl) {
      const int src = src_of_dest[slot];
      const float g = gval[slot];
      floatv4 xv = ((const floatv4*)(x + ((size_t)b * NS + src) * ND))[tid];
      r = xv * g;
    } else {
      r = (floatv4)(0.f);
    }
    __builtin_nontemporal_store(r, vo + tid);
  }
}

extern "C" void kernel_launch(void* const* d_in, const int* in_sizes, int n_in,
                              void* d_out, int out_size, void* d_ws, size_t ws_size,
                              hipStream_t stream) {
  const float* x   = (const float*)d_in[0];
  const int*   pad = (const int*)d_in[1];
  const float* W1  = (const float*)d_in[2];
  const float* b1  = (const float*)d_in[3];
  const float* W2  = (const float*)d_in[4];
  const float* b2  = (const float*)d_in[5];

  float* v    = (float*)d_out;                 // [8,4096,1024]
  float* vpad = v + (size_t)NTOK * ND;         // [8,4096]

  // Wf scratch inside d_out's v region: k1 reads it, k3 later overwrites all
  // of v (same-stream ordering makes this safe, incl. rocprof replay).
  unsigned short* Wf = (unsigned short*)(v + 24000000);  // 2 MB packed W

  // d_ws (~384 KB): ysq, gval, src map, new_len, rowmax
  float* ysq  = (float*)d_ws;                  // NTOK
  float* gval = ysq + NTOK;                    // NTOK
  int* src    = (int*)(gval + NTOK);           // NTOK
  int* nlen   = src + NTOK;                    // NB
  unsigned int* rowmax = (unsigned int*)(nlen + NB);  // NB

  k0_prep<<<64, 256, 0, stream>>>(W1, Wf, rowmax);
  k1_gemm<<<NTOK / 32, 256, 0, stream>>>(x, Wf, b1, W2, pad, b2, ysq, rowmax);
  k2b<<<NB, 256, 0, stream>>>(ysq, pad, rowmax, gval, src, nlen, vpad);
  k3_gather<<<NTOK / 16, 256, 0, stream>>>(x, gval, src, nlen, v);
}

// Round 3
// 335.737 us; speedup vs baseline: 2.8685x; 1.0639x over previous
//
#include <hip/hip_runtime.h>
#include <math.h>

// SoftGate: gate-MLP (split-bf16 MFMA, barrier-free) -> threshold -> compaction.
#define NB 8
#define NS 4096
#define ND 1024      // K (feature dim)
#define NDH 512      // N (hidden dim)
#define NTOK (NB*NS) // M = 32768
#define THRESH 0.1f
#define EPSV 1e-5f

using short8   = __attribute__((ext_vector_type(8)))  short;
using floatx16 = __attribute__((ext_vector_type(16))) float;
using floatv4  = __attribute__((ext_vector_type(4)))  float;  // native vec for nontemporal

__device__ __forceinline__ unsigned short f32_to_bf16_rne(float f) {
  union { float f; unsigned u; } v; v.f = f;
  unsigned r = v.u + 0x7fffu + ((v.u >> 16) & 1u);
  return (unsigned short)(r >> 16);
}
__device__ __forceinline__ float bf16_to_f32(unsigned short h) {
  union { unsigned u; float f; } v; v.u = ((unsigned)h) << 16;
  return v.f;
}

// pack 8 f32 (two float4) into split-bf16 hi/lo short8 fragments (RNE both).
__device__ __forceinline__ void cvt8_split(const float4& a, const float4& b,
                                           short8& hi, short8& lo) {
  float v8[8] = {a.x, a.y, a.z, a.w, b.x, b.y, b.z, b.w};
  unsigned hp[4], lp[4];
#pragma unroll
  for (int j = 0; j < 4; ++j) {
    unsigned short h0 = f32_to_bf16_rne(v8[2 * j]);
    unsigned short h1 = f32_to_bf16_rne(v8[2 * j + 1]);
    unsigned short l0 = f32_to_bf16_rne(v8[2 * j] - bf16_to_f32(h0));
    unsigned short l1 = f32_to_bf16_rne(v8[2 * j + 1] - bf16_to_f32(h1));
    hp[j] = (unsigned)h0 | ((unsigned)h1 << 16);
    lp[j] = (unsigned)l0 | ((unsigned)l1 << 16);
  }
  *(uint4*)&hi = make_uint4(hp[0], hp[1], hp[2], hp[3]);
  *(uint4*)&lo = make_uint4(lp[0], lp[1], lp[2], lp[3]);
}

// ---------------------------------------------------------------------------
// K0: repack W1 into MFMA-B-fragment order, bf16 hi/lo by 1 KB chunk:
//   chunk(n32,k16): lane l holds n=n32*32+(l&31), k=k16*16+(l>>5)*8+j.
// Also zero-inits rowmax for k1's fused atomicMax.  (identical to R5)
// ---------------------------------------------------------------------------
__global__ __launch_bounds__(256)
void k0_prep(const float* __restrict__ W1, unsigned short* __restrict__ Wf,
             unsigned int* __restrict__ rowmax) {
  __shared__ float sw[16][513];
  const int t = threadIdx.x;
  const int k16 = blockIdx.x;                // 0..63
  if (k16 == 0 && t < NB) rowmax[t] = 0u;
#pragma unroll
  for (int i = 0; i < 8; ++i) {
    int flat = i * 256 + t;
    int r = flat >> 7, c4 = (flat & 127) << 2;
    *(float4*)&sw[r][c4] = *(const float4*)(W1 + (size_t)(k16 * 16 + r) * NDH + c4);
  }
  __syncthreads();
#pragma unroll
  for (int q = 0; q < 4; ++q) {
    int ss = q * 256 + t;
    int n32 = ss >> 6, lane = ss & 63;
    int n = n32 * 32 + (lane & 31);
    int kb = (lane >> 5) * 8;
    unsigned hi2[4], lo2[4];
#pragma unroll
    for (int j = 0; j < 4; ++j) {
      float w0 = sw[kb + 2 * j][n], w1 = sw[kb + 2 * j + 1][n];
      unsigned short h0 = f32_to_bf16_rne(w0), h1 = f32_to_bf16_rne(w1);
      unsigned short l0 = f32_to_bf16_rne(w0 - bf16_to_f32(h0));
      unsigned short l1 = f32_to_bf16_rne(w1 - bf16_to_f32(h1));
      hi2[j] = (unsigned)h0 | ((unsigned)h1 << 16);
      lo2[j] = (unsigned)l0 | ((unsigned)l1 << 16);
    }
    size_t cb = ((size_t)(n32 * 64 + k16) * 2) * 512 + (size_t)lane * 8;
    *(uint4*)(Wf + cb)       = make_uint4(hi2[0], hi2[1], hi2[2], hi2[3]);
    *(uint4*)(Wf + cb + 512) = make_uint4(lo2[0], lo2[1], lo2[2], lo2[3]);
  }
}

// ---------------------------------------------------------------------------
// K1: fused gate MLP. 3-term split-bf16 MFMA (hi·hi + lo·hi + hi·lo), fp32 acc.
// R8: BARRIER-FREE. R5's 8 waves/CU were phase-locked by the staging barrier
// (2-phase stall, m233); R7 showed tile-shrink occupancy trades away compute
// density. Fix: each wave builds its OWN A-fragments from global (lane l
// reads 8+8 consecutive floats of row tok0+mt*32+(l&31), converts to bf16
// hi/lo in-register) -> no LDS staging, no __syncthreads in the K-loop.
// 2 waves/SIMD free-run: one wave's B-L2 latency + convert VALU hides under
// the other's 1536-cyc MFMA cluster. x prefetched 1 iter ahead in regs
// (R5 pattern) to cover the per-iter HBM line miss. 4x redundant x reads
// are L1/L2-absorbed (block waves share rows); HBM stays compulsory ~128MB.
// Numerics: conversions + per-acc accumulation order IDENTICAL to R5.
// Reg budget: acc 128 + xcur/xnxt 64 + B 32 + A 16 + addr ~= 240 <= 256
// (launch_bounds(256,2)). Tripwire: WRITE_SIZE must stay ~KB (no spill).
// BM=64 x N=512; wave w owns cols [128w,128w+128).
// ---------------------------------------------------------------------------
__global__ __launch_bounds__(256, 2)
void k1_gemm(const float* __restrict__ x, const unsigned short* __restrict__ Wf,
             const float* __restrict__ b1, const float* __restrict__ W2,
             const int* __restrict__ pad, const float* __restrict__ b2,
             float* __restrict__ ysq, unsigned int* __restrict__ rowmax) {
  __shared__ float red[4][64];

  const int tid = threadIdx.x;
  const int wave = tid >> 6, lane = tid & 63;
  const int l31 = lane & 31, h5 = lane >> 5;
  const int tok0 = blockIdx.x * 64;

  floatx16 acc[2][4];
#pragma unroll
  for (int mt = 0; mt < 2; ++mt)
#pragma unroll
    for (int nt = 0; nt < 4; ++nt)
#pragma unroll
      for (int r = 0; r < 16; ++r) acc[mt][nt][r] = 0.f;

  // per-lane A base: row tok0 + mt*32 + l31, k-offset h5*8 within each kh-16
  const float* xbase = x + (size_t)(tok0 + l31) * ND + h5 * 8;

  const unsigned short* wb[4];
#pragma unroll
  for (int nt = 0; nt < 4; ++nt)
    wb[nt] = Wf + (((size_t)(wave * 4 + nt) * 64) * 2) * 512 + (size_t)lane * 8;

  // x register double-buffer: [mt][kh][half] float4 pairs
  float4 xc[2][2][2], xn[2][2][2];
#pragma unroll
  for (int mt = 0; mt < 2; ++mt)
#pragma unroll
    for (int kh = 0; kh < 2; ++kh) {
      const float* xp = xbase + (size_t)mt * 32 * ND + kh * 16;
      xc[mt][kh][0] = *(const float4*)xp;
      xc[mt][kh][1] = *(const float4*)(xp + 4);
    }

  for (int it = 0; it < 32; ++it) {
    // prefetch x for it+1 (issued before MFMAs; ~900cy HBM latency hides)
    if (it < 31) {
#pragma unroll
      for (int mt = 0; mt < 2; ++mt)
#pragma unroll
        for (int kh = 0; kh < 2; ++kh) {
          const float* xp = xbase + (size_t)mt * 32 * ND + (it + 1) * 32 + kh * 16;
          xn[mt][kh][0] = *(const float4*)xp;
          xn[mt][kh][1] = *(const float4*)(xp + 4);
        }
    }
#pragma unroll
    for (int kh = 0; kh < 2; ++kh) {
      // B fragments for this kh (L2-resident; consumed progressively below)
      short8 bh[4], bl[4];
#pragma unroll
      for (int nt = 0; nt < 4; ++nt) {
        const unsigned short* q = wb[nt] + ((size_t)(2 * it + kh) * 2) * 512;
        bh[nt] = *(const short8*)(q);
        bl[nt] = *(const short8*)(q + 512);
      }
      // A fragments: in-register split-bf16 convert of prefetched x
      short8 ah[2], al[2];
#pragma unroll
      for (int mt = 0; mt < 2; ++mt)
        cvt8_split(xc[mt][kh][0], xc[mt][kh][1], ah[mt], al[mt]);
      // term-outer MFMA issue: 8 independent accs between same-acc reuse;
      // per-acc order (hh,lh,hl per kh) identical to R5.
#pragma unroll
      for (int nt = 0; nt < 4; ++nt)
#pragma unroll
        for (int mt = 0; mt < 2; ++mt)
          acc[mt][nt] = __builtin_amdgcn_mfma_f32_32x32x16_bf16(ah[mt], bh[nt], acc[mt][nt], 0, 0, 0);
#pragma unroll
      for (int nt = 0; nt < 4; ++nt)
#pragma unroll
        for (int mt = 0; mt < 2; ++mt)
          acc[mt][nt] = __builtin_amdgcn_mfma_f32_32x32x16_bf16(al[mt], bh[nt], acc[mt][nt], 0, 0, 0);
#pragma unroll
      for (int nt = 0; nt < 4; ++nt)
#pragma unroll
        for (int mt = 0; mt < 2; ++mt)
          acc[mt][nt] = __builtin_amdgcn_mfma_f32_32x32x16_bf16(ah[mt], bl[nt], acc[mt][nt], 0, 0, 0);
    }
    // rotate x double-buffer
    if (it < 31) {
#pragma unroll
      for (int mt = 0; mt < 2; ++mt)
#pragma unroll
        for (int kh = 0; kh < 2; ++kh) {
          xc[mt][kh][0] = xn[mt][kh][0];
          xc[mt][kh][1] = xn[mt][kh][1];
        }
    }
  }

  // epilogue: relu(h+b1)*W2, shfl-reduce 32 col-lanes, LDS combine.
  // C/D layout (m74/m101): col=lane&31, row=(r&3)+8*(r>>2)+4*(lane>>5)
  float b1v[4], w2v[4];
#pragma unroll
  for (int nt = 0; nt < 4; ++nt) {
    const int n = wave * 128 + nt * 32 + l31;
    b1v[nt] = b1[n];
    w2v[nt] = W2[n];
  }
#pragma unroll
  for (int mt = 0; mt < 2; ++mt) {
    float pr[16];
#pragma unroll
    for (int r = 0; r < 16; ++r) pr[r] = 0.f;
#pragma unroll
    for (int nt = 0; nt < 4; ++nt)
#pragma unroll
      for (int r = 0; r < 16; ++r)
        pr[r] += fmaxf(acc[mt][nt][r] + b1v[nt], 0.f) * w2v[nt];
#pragma unroll
    for (int m = 1; m <= 16; m <<= 1)
#pragma unroll
      for (int r = 0; r < 16; ++r) pr[r] += __shfl_xor(pr[r], m, 64);
    if (l31 == 0) {
#pragma unroll
      for (int r = 0; r < 16; ++r) {
        int row = (r & 3) + 8 * (r >> 2) + 4 * h5;
        red[wave][mt * 32 + row] = pr[r];
      }
    }
  }
  __syncthreads();
  // fused k2a: squash, pad-zero, store ysq, exact row max via atomicMax
  if (tid < 64) {
    float s = red[0][tid] + red[1][tid] + red[2][tid] + red[3][tid];
    const int t = tok0 + tid;
    float yl = s + b2[0];
    float y = (1.f + tanhf(10.f * yl)) * 0.5f;
    if (pad[t]) y = 0.f;
    ysq[t] = y;
    float m = y;
#pragma unroll
    for (int o = 32; o >= 1; o >>= 1) m = fmaxf(m, __shfl_xor(m, o, 64));
    if (tid == 0) atomicMax(rowmax + (t >> 12), __float_as_uint(m));
  }
}

// ---------------------------------------------------------------------------
// K2b: per row -- adjust, threshold, stable shfl-scan compaction map, new_len,
// v_pad, and gate value packed by DEST index (gval) so k3 reads it directly.
// (identical to R5)
// ---------------------------------------------------------------------------
__global__ __launch_bounds__(256)
void k2b(const float* __restrict__ ysq, const int* __restrict__ pad,
         const unsigned int* __restrict__ rowmax, float* __restrict__ gval,
         int* __restrict__ src_of_dest, int* __restrict__ new_len,
         float* __restrict__ vpad_out) {
  __shared__ int ssum[4];
  const int b = blockIdx.x, tid = threadIdx.x;
  const int lane = tid & 63, wv = tid >> 6;
  const int base = b * NS, s0 = tid * 16;
  const float adj = fmaxf(EPSV + THRESH - __uint_as_float(rowmax[b]), 0.f);

  float yv[16];
  unsigned km = 0;
  int cnt = 0;
#pragma unroll
  for (int i = 0; i < 16; ++i) {
    int s = s0 + i;
    float yf = ysq[base + s] + adj;
    yv[i] = yf;
    bool keep = (yf > THRESH) && !pad[base + s];
    if (keep) { km |= (1u << i); ++cnt; }
  }
  // wave inclusive scan of per-thread counts
  int inc = cnt;
#pragma unroll
  for (int o = 1; o < 64; o <<= 1) {
    int tmp = __shfl_up(inc, o, 64);
    if (lane >= o) inc += tmp;
  }
  if (lane == 63) ssum[wv] = inc;
  __syncthreads();
  int wpre = 0;
  for (int w = 0; w < wv; ++w) wpre += ssum[w];
  const int total = ssum[0] + ssum[1] + ssum[2] + ssum[3];
  int off = wpre + inc - cnt;   // exclusive offset, stable order
#pragma unroll
  for (int i = 0; i < 16; ++i) {
    int s = s0 + i;
    if ((km >> i) & 1u) {
      src_of_dest[base + off] = s;
      gval[base + off] = yv[i];
      ++off;
    }
    vpad_out[base + s] = (s >= total) ? 1.f : 0.f;
  }
  if (tid == 0) new_len[b] = total;
}

// ---------------------------------------------------------------------------
// K3: 16 output slots per block (2048 blocks): v = x[src]*gval or zeros.
// Nontemporal stores (native ext_vector float4) -- v is written once.
// (identical to R5)
// ---------------------------------------------------------------------------
__global__ __launch_bounds__(256)
void k3_gather(const float* __restrict__ x, const float* __restrict__ gval,
               const int* __restrict__ src_of_dest, const int* __restrict__ new_len,
               float* __restrict__ v) {
  const int slot0 = blockIdx.x * 16;
  const int b = slot0 >> 12;            // 16 | 4096 -> same row for all 16
  const int nl = new_len[b];
  const int tid = threadIdx.x;
#pragma unroll
  for (int i = 0; i < 16; ++i) {
    const int slot = slot0 + i;
    const int dest = slot & (NS - 1);
    floatv4* vo = (floatv4*)(v + (size_t)slot * ND);
    floatv4 r;
    if (dest < nl) {
      const int src = src_of_dest[slot];
      const float g = gval[slot];
      floatv4 xv = ((const floatv4*)(x + ((size_t)b * NS + src) * ND))[tid];
      r = xv * g;
    } else {
      r = (floatv4)(0.f);
    }
    __builtin_nontemporal_store(r, vo + tid);
  }
}

extern "C" void kernel_launch(void* const* d_in, const int* in_sizes, int n_in,
                              void* d_out, int out_size, void* d_ws, size_t ws_size,
                              hipStream_t stream) {
  const float* x   = (const float*)d_in[0];
  const int*   pad = (const int*)d_in[1];
  const float* W1  = (const float*)d_in[2];
  const float* b1  = (const float*)d_in[3];
  const float* W2  = (const float*)d_in[4];
  const float* b2  = (const float*)d_in[5];

  float* v    = (float*)d_out;                 // [8,4096,1024]
  float* vpad = v + (size_t)NTOK * ND;         // [8,4096]

  // Wf scratch inside d_out's v region: k1 reads it, k3 later overwrites all
  // of v (same-stream ordering makes this safe, incl. rocprof replay).
  unsigned short* Wf = (unsigned short*)(v + 24000000);  // 2 MB packed W

  // d_ws (~384 KB): ysq, gval, src map, new_len, rowmax
  float* ysq  = (float*)d_ws;                  // NTOK
  float* gval = ysq + NTOK;                    // NTOK
  int* src    = (int*)(gval + NTOK);           // NTOK
  int* nlen   = src + NTOK;                    // NB
  unsigned int* rowmax = (unsigned int*)(nlen + NB);  // NB

  k0_prep<<<64, 256, 0, stream>>>(W1, Wf, rowmax);
  k1_gemm<<<NTOK / 64, 256, 0, stream>>>(x, Wf, b1, W2, pad, b2, ysq, rowmax);
  k2b<<<NB, 256, 0, stream>>>(ysq, pad, rowmax, gval, src, nlen, vpad);
  k3_gather<<<NTOK / 16, 256, 0, stream>>>(x, gval, src, nlen, v);
}

// Round 4
// 315.399 us; speedup vs baseline: 3.0535x; 1.0645x over previous
//
#include <hip/hip_runtime.h>
#include <math.h>

// SoftGate: gate-MLP (split-bf16 MFMA, pipelined) -> threshold -> compaction.
#define NB 8
#define NS 4096
#define ND 1024      // K (feature dim)
#define NDH 512      // N (hidden dim)
#define NTOK (NB*NS) // M = 32768
#define THRESH 0.1f
#define EPSV 1e-5f

using short8   = __attribute__((ext_vector_type(8)))  short;
using floatx16 = __attribute__((ext_vector_type(16))) float;
using floatv4  = __attribute__((ext_vector_type(4)))  float;  // native vec for nontemporal

__device__ __forceinline__ unsigned short f32_to_bf16_rne(float f) {
  union { float f; unsigned u; } v; v.f = f;
  unsigned r = v.u + 0x7fffu + ((v.u >> 16) & 1u);
  return (unsigned short)(r >> 16);
}
__device__ __forceinline__ float bf16_to_f32(unsigned short h) {
  union { unsigned u; float f; } v; v.u = ((unsigned)h) << 16;
  return v.f;
}

// ---------------------------------------------------------------------------
// K0: repack W1 into MFMA-B-fragment order, bf16 hi/lo by 1 KB chunk:
//   chunk(n32,k16): lane l holds n=n32*32+(l&31), k=k16*16+(l>>5)*8+j.
// Also zero-inits rowmax for k1's fused atomicMax.  (identical to R5)
// ---------------------------------------------------------------------------
__global__ __launch_bounds__(256)
void k0_prep(const float* __restrict__ W1, unsigned short* __restrict__ Wf,
             unsigned int* __restrict__ rowmax) {
  __shared__ float sw[16][513];
  const int t = threadIdx.x;
  const int k16 = blockIdx.x;                // 0..63
  if (k16 == 0 && t < NB) rowmax[t] = 0u;
#pragma unroll
  for (int i = 0; i < 8; ++i) {
    int flat = i * 256 + t;
    int r = flat >> 7, c4 = (flat & 127) << 2;
    *(float4*)&sw[r][c4] = *(const float4*)(W1 + (size_t)(k16 * 16 + r) * NDH + c4);
  }
  __syncthreads();
#pragma unroll
  for (int q = 0; q < 4; ++q) {
    int ss = q * 256 + t;
    int n32 = ss >> 6, lane = ss & 63;
    int n = n32 * 32 + (lane & 31);
    int kb = (lane >> 5) * 8;
    unsigned hi2[4], lo2[4];
#pragma unroll
    for (int j = 0; j < 4; ++j) {
      float w0 = sw[kb + 2 * j][n], w1 = sw[kb + 2 * j + 1][n];
      unsigned short h0 = f32_to_bf16_rne(w0), h1 = f32_to_bf16_rne(w1);
      unsigned short l0 = f32_to_bf16_rne(w0 - bf16_to_f32(h0));
      unsigned short l1 = f32_to_bf16_rne(w1 - bf16_to_f32(h1));
      hi2[j] = (unsigned)h0 | ((unsigned)h1 << 16);
      lo2[j] = (unsigned)l0 | ((unsigned)l1 << 16);
    }
    size_t cb = ((size_t)(n32 * 64 + k16) * 2) * 512 + (size_t)lane * 8;
    *(uint4*)(Wf + cb)       = make_uint4(hi2[0], hi2[1], hi2[2], hi2[3]);
    *(uint4*)(Wf + cb + 512) = make_uint4(lo2[0], lo2[1], lo2[2], lo2[3]);
  }
}

// ---------------------------------------------------------------------------
// K1: fused gate MLP. 3-term split-bf16 MFMA (hi·hi + lo·hi + hi·lo), fp32 acc.
// R9: exact R5 structure (cooperative LDS staging, 4 waves, BM=64xN=512,
// term-outer MFMA issue, reg x-prefetch) with ONE change: BK 32->64, so 16
// barrier phases instead of 32. Rationale: m233-style stage+drain+barrier
// overhead is per-phase and was ~60% of R5's wall (MfmaUtil 37 + VALU 14);
// doubling MFMAs per phase amortizes it. B frags loaded per-k16 inside the
// phase (32 regs live vs 64) to keep unified regs ~230 <= 256 @ 2 waves/SIMD.
// Numerics: same k16 visit order, same per-acc term order (hh,lh,hl per k16),
// same RNE converts -> bit-identical to R5.
// Tripwire: WRITE_SIZE must stay ~144 KB (no scratch spill).
// ---------------------------------------------------------------------------
__global__ __launch_bounds__(256, 2)
void k1_gemm(const float* __restrict__ x, const unsigned short* __restrict__ Wf,
             const float* __restrict__ b1, const float* __restrict__ W2,
             const int* __restrict__ pad, const float* __restrict__ b2,
             float* __restrict__ ysq, unsigned int* __restrict__ rowmax) {
  __shared__ __align__(16) unsigned short sx[2][2][64 * 72];  // [buf][hi/lo][m*72+k]
  __shared__ float red[4][64];

  const int tid = threadIdx.x;
  const int wave = tid >> 6, lane = tid & 63;
  const int l31 = lane & 31, h5 = lane >> 5;
  const int tok0 = blockIdx.x * 64;

  floatx16 acc[2][4];
#pragma unroll
  for (int mt = 0; mt < 2; ++mt)
#pragma unroll
    for (int nt = 0; nt < 4; ++nt)
#pragma unroll
      for (int r = 0; r < 16; ++r) acc[mt][nt][r] = 0.f;

  const int sm = tid >> 2;            // staging row 0..63 (4 threads/row)
  const int sk = (tid & 3) * 16;      // staging k-offset {0,16,32,48}
  const float* xrow = x + (size_t)(tok0 + sm) * ND + sk;

  const unsigned short* wb[4];
#pragma unroll
  for (int nt = 0; nt < 4; ++nt)
    wb[nt] = Wf + (((size_t)(wave * 4 + nt) * 64) * 2) * 512 + (size_t)lane * 8;

  // convert+store 16 staged floats (4x float4) into LDS buffer bf
  auto stage_cvt = [&](int bf, const float4& a0, const float4& a1,
                       const float4& a2, const float4& a3) {
    float v16[16] = {a0.x, a0.y, a0.z, a0.w, a1.x, a1.y, a1.z, a1.w,
                     a2.x, a2.y, a2.z, a2.w, a3.x, a3.y, a3.z, a3.w};
    unsigned hp[8], lp[8];
#pragma unroll
    for (int j = 0; j < 8; ++j) {
      unsigned short h0 = f32_to_bf16_rne(v16[2 * j]);
      unsigned short h1 = f32_to_bf16_rne(v16[2 * j + 1]);
      unsigned short l0 = f32_to_bf16_rne(v16[2 * j] - bf16_to_f32(h0));
      unsigned short l1 = f32_to_bf16_rne(v16[2 * j + 1] - bf16_to_f32(h1));
      hp[j] = (unsigned)h0 | ((unsigned)h1 << 16);
      lp[j] = (unsigned)l0 | ((unsigned)l1 << 16);
    }
    *(uint4*)&sx[bf][0][sm * 72 + sk]     = make_uint4(hp[0], hp[1], hp[2], hp[3]);
    *(uint4*)&sx[bf][0][sm * 72 + sk + 8] = make_uint4(hp[4], hp[5], hp[6], hp[7]);
    *(uint4*)&sx[bf][1][sm * 72 + sk]     = make_uint4(lp[0], lp[1], lp[2], lp[3]);
    *(uint4*)&sx[bf][1][sm * 72 + sk + 8] = make_uint4(lp[4], lp[5], lp[6], lp[7]);
  };

  // prologue: stage x for it=0 into LDS buf 0
  {
    float4 a0 = *(const float4*)xrow;
    float4 a1 = *(const float4*)(xrow + 4);
    float4 a2 = *(const float4*)(xrow + 8);
    float4 a3 = *(const float4*)(xrow + 12);
    stage_cvt(0, a0, a1, a2, a3);
  }

  for (int it = 0; it < 16; ++it) {
    const int p = it & 1;
    __syncthreads();                  // LDS[p] ready; prev-iter prefetch drained
    // x prefetch for NEXT iter: issued first, consumed after the MFMA phase
    float4 pa0, pa1, pa2, pa3;
    if (it < 15) {
      const float* xp = xrow + (it + 1) * 64;
      pa0 = *(const float4*)xp;
      pa1 = *(const float4*)(xp + 4);
      pa2 = *(const float4*)(xp + 8);
      pa3 = *(const float4*)(xp + 12);
    }
    // 4 k16-subphases per barrier phase; B frags loaded per-k16 (progressive
    // vmcnt: k16+1's loads issue during k16's MFMAs).
#pragma unroll
    for (int kh = 0; kh < 4; ++kh) {
      short8 bh[4], bl[4];
#pragma unroll
      for (int nt = 0; nt < 4; ++nt) {
        const unsigned short* q = wb[nt] + ((size_t)(4 * it + kh) * 2) * 512;
        bh[nt] = *(const short8*)(q);
        bl[nt] = *(const short8*)(q + 512);
      }
      // A fragments: lane holds x[tok=mt*32+l31][k = kh*16 + h5*8 + j]
      short8 ah[2], al[2];
#pragma unroll
      for (int mt = 0; mt < 2; ++mt) {
        ah[mt] = *(const short8*)&sx[p][0][(mt * 32 + l31) * 72 + kh * 16 + h5 * 8];
        al[mt] = *(const short8*)&sx[p][1][(mt * 32 + l31) * 72 + kh * 16 + h5 * 8];
      }
      // term-outer MFMA issue: 8 independent accs between same-acc reuse;
      // per-acc order per k16 (hh,lh,hl) identical to R5.
#pragma unroll
      for (int nt = 0; nt < 4; ++nt)
#pragma unroll
        for (int mt = 0; mt < 2; ++mt)
          acc[mt][nt] = __builtin_amdgcn_mfma_f32_32x32x16_bf16(ah[mt], bh[nt], acc[mt][nt], 0, 0, 0);
#pragma unroll
      for (int nt = 0; nt < 4; ++nt)
#pragma unroll
        for (int mt = 0; mt < 2; ++mt)
          acc[mt][nt] = __builtin_amdgcn_mfma_f32_32x32x16_bf16(al[mt], bh[nt], acc[mt][nt], 0, 0, 0);
#pragma unroll
      for (int nt = 0; nt < 4; ++nt)
#pragma unroll
        for (int mt = 0; mt < 2; ++mt)
          acc[mt][nt] = __builtin_amdgcn_mfma_f32_32x32x16_bf16(ah[mt], bl[nt], acc[mt][nt], 0, 0, 0);
    }
    // convert prefetched x -> other LDS buffer (ready for next barrier)
    if (it < 15) stage_cvt(p ^ 1, pa0, pa1, pa2, pa3);
  }

  // epilogue: relu(h+b1)*W2, shfl-reduce 32 col-lanes, LDS combine.
  // C/D layout (m74/m101): col=lane&31, row=(r&3)+8*(r>>2)+4*(lane>>5)
  float b1v[4], w2v[4];
#pragma unroll
  for (int nt = 0; nt < 4; ++nt) {
    const int n = wave * 128 + nt * 32 + l31;
    b1v[nt] = b1[n];
    w2v[nt] = W2[n];
  }
#pragma unroll
  for (int mt = 0; mt < 2; ++mt) {
    float pr[16];
#pragma unroll
    for (int r = 0; r < 16; ++r) pr[r] = 0.f;
#pragma unroll
    for (int nt = 0; nt < 4; ++nt)
#pragma unroll
      for (int r = 0; r < 16; ++r)
        pr[r] += fmaxf(acc[mt][nt][r] + b1v[nt], 0.f) * w2v[nt];
#pragma unroll
    for (int m = 1; m <= 16; m <<= 1)
#pragma unroll
      for (int r = 0; r < 16; ++r) pr[r] += __shfl_xor(pr[r], m, 64);
    if (l31 == 0) {
#pragma unroll
      for (int r = 0; r < 16; ++r) {
        int row = (r & 3) + 8 * (r >> 2) + 4 * h5;
        red[wave][mt * 32 + row] = pr[r];
      }
    }
  }
  __syncthreads();
  // fused k2a: squash, pad-zero, store ysq, exact row max via atomicMax
  if (tid < 64) {
    float s = red[0][tid] + red[1][tid] + red[2][tid] + red[3][tid];
    const int t = tok0 + tid;
    float yl = s + b2[0];
    float y = (1.f + tanhf(10.f * yl)) * 0.5f;
    if (pad[t]) y = 0.f;
    ysq[t] = y;
    float m = y;
#pragma unroll
    for (int o = 32; o >= 1; o >>= 1) m = fmaxf(m, __shfl_xor(m, o, 64));
    if (tid == 0) atomicMax(rowmax + (t >> 12), __float_as_uint(m));
  }
}

// ---------------------------------------------------------------------------
// K2b: per row -- adjust, threshold, stable shfl-scan compaction map, new_len,
// v_pad, gate value packed by DEST index. R9: 1024 threads (4 elems/thread)
// -- 8-block latency-bound kernel, 4x thread parallelism shortens the serial
// per-thread element loops. Stable order preserved (tid order = s order).
// ---------------------------------------------------------------------------
__global__ __launch_bounds__(1024)
void k2b(const float* __restrict__ ysq, const int* __restrict__ pad,
         const unsigned int* __restrict__ rowmax, float* __restrict__ gval,
         int* __restrict__ src_of_dest, int* __restrict__ new_len,
         float* __restrict__ vpad_out) {
  __shared__ int ssum[16];
  const int b = blockIdx.x, tid = threadIdx.x;
  const int lane = tid & 63, wv = tid >> 6;
  const int base = b * NS, s0 = tid * 4;
  const float adj = fmaxf(EPSV + THRESH - __uint_as_float(rowmax[b]), 0.f);

  float4 yq = *(const float4*)(ysq + base + s0);
  int4 pq = *(const int4*)(pad + base + s0);
  float yv[4] = {yq.x + adj, yq.y + adj, yq.z + adj, yq.w + adj};
  int pv[4] = {pq.x, pq.y, pq.z, pq.w};
  unsigned km = 0;
  int cnt = 0;
#pragma unroll
  for (int i = 0; i < 4; ++i) {
    bool keep = (yv[i] > THRESH) && !pv[i];
    if (keep) { km |= (1u << i); ++cnt; }
  }
  // wave inclusive scan of per-thread counts
  int inc = cnt;
#pragma unroll
  for (int o = 1; o < 64; o <<= 1) {
    int tmp = __shfl_up(inc, o, 64);
    if (lane >= o) inc += tmp;
  }
  if (lane == 63) ssum[wv] = inc;
  __syncthreads();
  int wpre = 0;
  int total = 0;
#pragma unroll
  for (int w = 0; w < 16; ++w) {
    int sv = ssum[w];
    if (w < wv) wpre += sv;
    total += sv;
  }
  int off = wpre + inc - cnt;   // exclusive offset, stable order
#pragma unroll
  for (int i = 0; i < 4; ++i) {
    int s = s0 + i;
    if ((km >> i) & 1u) {
      src_of_dest[base + off] = s;
      gval[base + off] = yv[i];
      ++off;
    }
    vpad_out[base + s] = (s >= total) ? 1.f : 0.f;
  }
  if (tid == 0) new_len[b] = total;
}

// ---------------------------------------------------------------------------
// K3: 16 output slots per block (2048 blocks): v = x[src]*gval or zeros.
// Nontemporal stores (native ext_vector float4) -- v is written once.
// (identical to R5)
// ---------------------------------------------------------------------------
__global__ __launch_bounds__(256)
void k3_gather(const float* __restrict__ x, const float* __restrict__ gval,
               const int* __restrict__ src_of_dest, const int* __restrict__ new_len,
               float* __restrict__ v) {
  const int slot0 = blockIdx.x * 16;
  const int b = slot0 >> 12;            // 16 | 4096 -> same row for all 16
  const int nl = new_len[b];
  const int tid = threadIdx.x;
#pragma unroll
  for (int i = 0; i < 16; ++i) {
    const int slot = slot0 + i;
    const int dest = slot & (NS - 1);
    floatv4* vo = (floatv4*)(v + (size_t)slot * ND);
    floatv4 r;
    if (dest < nl) {
      const int src = src_of_dest[slot];
      const float g = gval[slot];
      floatv4 xv = ((const floatv4*)(x + ((size_t)b * NS + src) * ND))[tid];
      r = xv * g;
    } else {
      r = (floatv4)(0.f);
    }
    __builtin_nontemporal_store(r, vo + tid);
  }
}

extern "C" void kernel_launch(void* const* d_in, const int* in_sizes, int n_in,
                              void* d_out, int out_size, void* d_ws, size_t ws_size,
                              hipStream_t stream) {
  const float* x   = (const float*)d_in[0];
  const int*   pad = (const int*)d_in[1];
  const float* W1  = (const float*)d_in[2];
  const float* b1  = (const float*)d_in[3];
  const float* W2  = (const float*)d_in[4];
  const float* b2  = (const float*)d_in[5];

  float* v    = (float*)d_out;                 // [8,4096,1024]
  float* vpad = v + (size_t)NTOK * ND;         // [8,4096]

  // Wf scratch inside d_out's v region: k1 reads it, k3 later overwrites all
  // of v (same-stream ordering makes this safe, incl. rocprof replay).
  unsigned short* Wf = (unsigned short*)(v + 24000000);  // 2 MB packed W

  // d_ws (~384 KB): ysq, gval, src map, new_len, rowmax
  float* ysq  = (float*)d_ws;                  // NTOK
  float* gval = ysq + NTOK;                    // NTOK
  int* src    = (int*)(gval + NTOK);           // NTOK
  int* nlen   = src + NTOK;                    // NB
  unsigned int* rowmax = (unsigned int*)(nlen + NB);  // NB

  k0_prep<<<64, 256, 0, stream>>>(W1, Wf, rowmax);
  k1_gemm<<<NTOK / 64, 256, 0, stream>>>(x, Wf, b1, W2, pad, b2, ysq, rowmax);
  k2b<<<NB, 1024, 0, stream>>>(ysq, pad, rowmax, gval, src, nlen, vpad);
  k3_gather<<<NTOK / 16, 256, 0, stream>>>(x, gval, src, nlen, v);
}